// Round 7
// baseline (200.254 us; speedup 1.0000x reference)
//
#include <hip/hip_runtime.h>
#include <stdint.h>
#include <math.h>

#define H 8
#define DH 64
#define T 2048
#define D 512
#define B 2
#define BH 16
#define MAXREL 32
#define NREL (2*MAXREL+1)
#define C1 0.18033688f           /* 0.125 * log2(e) */
#define NW (D*D)
#define NSPLIT 4
#define NKIT (T/NSPLIT/64)        /* 8 key tiles per split */

typedef _Float16 half_t;
typedef half_t half8 __attribute__((ext_vector_type(8)));
typedef half_t half4 __attribute__((ext_vector_type(4)));
typedef float f32x4 __attribute__((ext_vector_type(4)));
typedef int int2v __attribute__((ext_vector_type(2)));

typedef __attribute__((address_space(3))) unsigned int lds_uint;
typedef const __attribute__((address_space(1))) unsigned int glb_uint;

__device__ __forceinline__ void gl_lds16(const void* g, void* l) {
    __builtin_amdgcn_global_load_lds((glb_uint*)g, (lds_uint*)l, 16, 0, 0);
}
__device__ __forceinline__ f32x4 zero4() { f32x4 z = {0.f,0.f,0.f,0.f}; return z; }
__device__ __forceinline__ int pkrtz(float a, float b) {
    return __builtin_bit_cast(int, __builtin_amdgcn_cvt_pkrtz(a, b));
}

// ---------------------------------------------------------------------------
// prep: blocks [0,1024): X fp32 -> fp16.  blocks [1024,1280): W^T fp16.
// ---------------------------------------------------------------------------
__global__ __launch_bounds__(256) void prep(
    const float* __restrict__ X,
    const float* __restrict__ Wq, const float* __restrict__ Wk,
    const float* __restrict__ Wv, const float* __restrict__ Wo,
    half_t* __restrict__ Xh, half_t* __restrict__ Wts)
{
    __shared__ half_t Ld[64 * 72];
    const int bid = blockIdx.x;
    const int tid = threadIdx.x;
    if (bid < 1024) {
        const int i = (bid * 256 + tid) * 8;
        const float4 a = *(const float4*)(X + i);
        const float4 b = *(const float4*)(X + i + 4);
        half8 o;
        o[0]=(half_t)a.x; o[1]=(half_t)a.y; o[2]=(half_t)a.z; o[3]=(half_t)a.w;
        o[4]=(half_t)b.x; o[5]=(half_t)b.y; o[6]=(half_t)b.z; o[7]=(half_t)b.w;
        *(half8*)(Xh + i) = o;
    } else {
        const int id = bid - 1024;
        const int z = id >> 6;
        const int tile = id & 63;
        const float* __restrict__ W = (z==0)?Wq:(z==1)?Wk:(z==2)?Wv:Wo;
        half_t* __restrict__ out = Wts + (size_t)z * NW;
        const int k0 = (tile >> 3) * 64;
        const int n0 = (tile & 7) * 64;
        const int r = tid >> 2, c16 = (tid & 3) * 16;
        const float* src = W + (size_t)(k0 + r) * D + n0 + c16;
        #pragma unroll
        for (int j = 0; j < 16; ++j) Ld[r * 72 + c16 + j] = (half_t)src[j];
        __syncthreads();
        half_t tmp[16];
        #pragma unroll
        for (int j = 0; j < 16; ++j) tmp[j] = Ld[(c16 + j) * 72 + r];
        half8* dst = (half8*)(out + (size_t)(n0 + r) * D + k0 + c16);
        dst[0] = *(half8*)&tmp[0];
        dst[1] = *(half8*)&tmp[8];
    }
}

// ---------------------------------------------------------------------------
// QKV GEMM: C = Xh(4096x512) @ W + b.  64m x 128n, BK=64, dbuf staging,
// XOR(r&7)-swizzled 128B LDS rows.  z=0 Q; z=1 K; z=2 V transposed.
// ---------------------------------------------------------------------------
__global__ __launch_bounds__(256) void gemm_qkv(
    const half_t* __restrict__ Xh, const half_t* __restrict__ Wts,
    const float* __restrict__ bq, const float* __restrict__ bk,
    const float* __restrict__ bv,
    half_t* __restrict__ Qh, half_t* __restrict__ Kh, half_t* __restrict__ Vth)
{
    __shared__ half_t As[2][64 * 64];
    __shared__ half_t Bs[2][128 * 64];
    const int tid = threadIdx.x, w = tid >> 6, lane = tid & 63;
    const int l15 = lane & 15, quad = lane >> 4;
    const int m0 = blockIdx.x * 64, n0 = blockIdx.y * 128, z = blockIdx.z;
    const half_t* __restrict__ Wt = Wts + (size_t)z * NW;
    const float* __restrict__ bias = (z==0)?bq:(z==1)?bk:bv;

    auto stage = [&](int buf, int k0) {
        #pragma unroll
        for (int s = 0; s < 2; ++s) {
            const int cid = (w * 2 + s) * 64 + lane;
            const int r = cid >> 3, c = (cid & 7) ^ (r & 7);
            gl_lds16(Xh + (size_t)(m0 + r) * D + k0 + c * 8,
                     &As[buf][(w * 2 + s) * 512]);
        }
        #pragma unroll
        for (int s = 0; s < 4; ++s) {
            const int cid = (w * 4 + s) * 64 + lane;
            const int r = cid >> 3, c = (cid & 7) ^ (r & 7);
            gl_lds16(Wt + (size_t)(n0 + r) * D + k0 + c * 8,
                     &Bs[buf][(w * 4 + s) * 512]);
        }
    };

    f32x4 acc[4][2];
    #pragma unroll
    for (int ms = 0; ms < 4; ++ms) { acc[ms][0] = zero4(); acc[ms][1] = zero4(); }

    stage(0, 0);
    __syncthreads();
    for (int it = 0; it < 8; ++it) {
        const int cur = it & 1;
        if (it < 7) stage(cur ^ 1, (it + 1) * 64);
        const int swiz = l15 & 7;
        #pragma unroll
        for (int ks = 0; ks < 2; ++ks) {
            const int c = (ks * 4 + quad) ^ swiz;
            half8 bf[2];
            #pragma unroll
            for (int nt = 0; nt < 2; ++nt)
                bf[nt] = *(const half8*)&Bs[cur][(w * 32 + nt * 16 + l15) * 64 + c * 8];
            #pragma unroll
            for (int ms = 0; ms < 4; ++ms) {
                const half8 af = *(const half8*)&As[cur][(ms * 16 + l15) * 64 + c * 8];
                acc[ms][0] = __builtin_amdgcn_mfma_f32_16x16x32_f16(af, bf[0], acc[ms][0], 0, 0, 0);
                acc[ms][1] = __builtin_amdgcn_mfma_f32_16x16x32_f16(af, bf[1], acc[ms][1], 0, 0, 0);
            }
        }
        __syncthreads();
    }

    float bvv[2];
    #pragma unroll
    for (int nt = 0; nt < 2; ++nt) bvv[nt] = bias[n0 + w * 32 + nt * 16 + l15];

    if (z == 2) {
        #pragma unroll
        for (int ms = 0; ms < 4; ++ms) {
            const int mbase = m0 + ms * 16 + quad * 4;
            const int bb = mbase >> 11, t0 = mbase & 2047;
            #pragma unroll
            for (int nt = 0; nt < 2; ++nt) {
                const int n = n0 + w * 32 + nt * 16 + l15;
                const int hh = n >> 6, d = n & 63;
                half4 pk;
                #pragma unroll
                for (int r = 0; r < 4; ++r) pk[r] = (half_t)(acc[ms][nt][r] + bvv[nt]);
                *(half4*)(Vth + (((size_t)bb * H + hh) * DH + d) * T + t0) = pk;
            }
        }
    } else {
        half_t* __restrict__ dst = (z == 0) ? Qh : Kh;
        #pragma unroll
        for (int ms = 0; ms < 4; ++ms)
            #pragma unroll
            for (int nt = 0; nt < 2; ++nt)
                #pragma unroll
                for (int r = 0; r < 4; ++r) {
                    const int mrow = m0 + ms * 16 + quad * 4 + r;
                    const int n = n0 + w * 32 + nt * 16 + l15;
                    const int bb = mrow >> 11, t = mrow & 2047, hh = n >> 6, d = n & 63;
                    dst[(((size_t)bb * H + hh) * T + t) * DH + d] = (half_t)(acc[ms][nt][r] + bvv[nt]);
                }
    }
}

// ---------------------------------------------------------------------------
// Flash attention, zero-LDS / zero-barrier.  Wave = 32 q; block = 4 waves
// (independent).  grid (16, 16, 4 splits).  Per 64-key tile:
//   S^T = K.Q^T  (16x16x32, K-frags direct from global)
//   softmax (exp2, no max — S bounded); P packs DIRECTLY into the
//   16x16x16 B-fragment layout (C rows quad*4+r == B k=quad*4+j) — no shuffle
//   O^T += V^T.P^T (16x16x16, V-frags direct from global)
// Writes unnormalized O/64 fp16 + rowsum l/64 fp16.
// ---------------------------------------------------------------------------
__global__ __launch_bounds__(256, 3) void attn_fwd(
    const half_t* __restrict__ Qh, const half_t* __restrict__ Kh,
    const half_t* __restrict__ Vth, const float* __restrict__ relb,
    half_t* __restrict__ On01, half_t* __restrict__ On23,
    half_t* __restrict__ lsum)
{
    __shared__ float rb2[NREL];

    const int tid = threadIdx.x, w = tid >> 6, lane = tid & 63;
    const int l15 = lane & 15, quad = lane >> 4;
    const int qw = blockIdx.x * 128 + w * 32;   // this wave's 32 q-rows
    const int bh = blockIdx.y;
    const int split = blockIdx.z;
    const int kb0 = split * (T / NSPLIT);
    const int h = bh & 7;

    if (tid < NREL) rb2[tid] = relb[h * NREL + tid] * 1.44269504f;
    __syncthreads();   // the only block-wide barrier

    // Q as B-operand (16x16x32): n=l15, k=ks*32+quad*8
    half8 qf[2][2];
    const half_t* Qbase = Qh + ((size_t)bh * T + qw) * DH;
    #pragma unroll
    for (int g = 0; g < 2; ++g)
        #pragma unroll
        for (int ks = 0; ks < 2; ++ks)
            qf[g][ks] = *(const half8*)(Qbase + (g * 16 + l15) * DH + ks * 32 + quad * 8);

    const half_t* Kp = Kh + (size_t)bh * T * DH;     // [t][d]
    const half_t* Vp = Vth + (size_t)bh * DH * T;    // [d][t]

    f32x4 of[2][4];   // [g][d-mtile]; C: col=l15=q, row=quad*4+r=d
    #pragma unroll
    for (int g = 0; g < 2; ++g)
        #pragma unroll
        for (int mt = 0; mt < 4; ++mt) of[g][mt] = zero4();
    float lp[2] = {0.f, 0.f};

    for (int it = 0; it < NKIT; ++it) {
        const int kb = kb0 + it * 64;

        // S^T = K . Q^T : A = K-frag (m=key) read straight from global
        f32x4 st[2][4];   // [g][key-nt]
        #pragma unroll
        for (int g = 0; g < 2; ++g)
            #pragma unroll
            for (int nt = 0; nt < 4; ++nt) st[g][nt] = zero4();
        #pragma unroll
        for (int ks = 0; ks < 2; ++ks)
            #pragma unroll
            for (int nt = 0; nt < 4; ++nt) {
                const half8 kf = *(const half8*)(Kp + (size_t)(kb + nt * 16 + l15) * DH
                                                 + ks * 32 + quad * 8);
                st[0][nt] = __builtin_amdgcn_mfma_f32_16x16x32_f16(kf, qf[0][ks], st[0][nt], 0, 0, 0);
                st[1][nt] = __builtin_amdgcn_mfma_f32_16x16x32_f16(kf, qf[1][ks], st[1][nt], 0, 0, 0);
            }

        // softmax; pack P directly into 16x16x16 B-frag layout (k=quad*4+j)
        half4 pf[2][4];   // [g][key-seg of 16]
        const bool uni_hi = (qw - (kb + 63)) >= MAXREL;
        const bool uni_lo = ((qw + 31) - kb) <= -MAXREL;
        if (uni_hi || uni_lo) {
            const float bu = uni_hi ? rb2[NREL - 1] : rb2[0];
            #pragma unroll
            for (int g = 0; g < 2; ++g)
                #pragma unroll
                for (int nt = 0; nt < 4; ++nt) {
                    float p[4];
                    #pragma unroll
                    for (int r = 0; r < 4; ++r) p[r] = exp2f(fmaf(st[g][nt][r], C1, bu));
                    lp[g] += (p[0] + p[1]) + (p[2] + p[3]);
                    int2v pk; pk[0] = pkrtz(p[0], p[1]); pk[1] = pkrtz(p[2], p[3]);
                    pf[g][nt] = __builtin_bit_cast(half4, pk);
                }
        } else {
            #pragma unroll
            for (int g = 0; g < 2; ++g) {
                const int qg = qw + g * 16 + l15;
                #pragma unroll
                for (int nt = 0; nt < 4; ++nt) {
                    float p[4];
                    #pragma unroll
                    for (int r = 0; r < 4; ++r) {
                        const int key = kb + nt * 16 + quad * 4 + r;
                        int rel = qg - key;
                        rel = rel < -MAXREL ? -MAXREL : (rel > MAXREL ? MAXREL : rel);
                        p[r] = exp2f(fmaf(st[g][nt][r], C1, rb2[rel + MAXREL]));
                    }
                    lp[g] += (p[0] + p[1]) + (p[2] + p[3]);
                    int2v pk; pk[0] = pkrtz(p[0], p[1]); pk[1] = pkrtz(p[2], p[3]);
                    pf[g][nt] = __builtin_bit_cast(half4, pk);
                }
            }
        }

        // O^T += V^T . P^T : A = V^T-frag (m=d, k=quad*4+j) direct from global
        #pragma unroll
        for (int nt = 0; nt < 4; ++nt) {      // key segment (k of PV)
            #pragma unroll
            for (int mt = 0; mt < 4; ++mt) {  // d tile
                const half4 vf = *(const half4*)(Vp + (size_t)(mt * 16 + l15) * T
                                                 + kb + nt * 16 + quad * 4);
                of[0][mt] = __builtin_amdgcn_mfma_f32_16x16x16f16(vf, pf[0][nt], of[0][mt], 0, 0, 0);
                of[1][mt] = __builtin_amdgcn_mfma_f32_16x16x16f16(vf, pf[1][nt], of[1][mt], 0, 0, 0);
            }
        }
    }

    // epilogue: lane holds O^T for q = qw + g*16 + l15, d = mt*16 + quad*4 + r
    half_t* Obuf = (split < 2) ? On01 : On23;
    const int sl = split & 1;
    #pragma unroll
    for (int g = 0; g < 2; ++g) {
        const size_t qrow = ((size_t)(sl * BH + bh)) * T + qw + g * 16 + l15;
        half_t* obase = Obuf + qrow * DH;
        #pragma unroll
        for (int mt = 0; mt < 4; ++mt) {
            half4 pk;
            #pragma unroll
            for (int r = 0; r < 4; ++r) pk[r] = (half_t)(of[g][mt][r] * 0.015625f);
            *(half4*)(obase + mt * 16 + quad * 4) = pk;
        }
        float v = lp[g];
        v += __shfl_xor(v, 16);
        v += __shfl_xor(v, 32);
        if (quad == 0)
            lsum[((size_t)(split * BH + bh)) * T + qw + g * 16 + l15] = (half_t)(v * 0.015625f);
    }
}

// ---------------------------------------------------------------------------
// Combine 4 splits: AOh[t][h*64+d] = sum(O_s)/sum(l_s), fp16.  grid 1024x256.
// ---------------------------------------------------------------------------
__global__ __launch_bounds__(256) void combine(
    const half_t* __restrict__ On01, const half_t* __restrict__ On23,
    const half_t* __restrict__ lsum, half_t* __restrict__ AOh)
{
    const int i = blockIdx.x * 256 + threadIdx.x;
    const int r = i >> 6;
    const int c = (i & 63) * 8;
    const int b = r >> 11, t = r & 2047, hh = c >> 6, d = c & 63;
    const int bh = b * H + hh;
    float acc[8] = {};
    float l = 0.f;
    #pragma unroll
    for (int s = 0; s < NSPLIT; ++s) {
        const half_t* Obuf = (s < 2) ? On01 : On23;
        const size_t off = ((size_t)((s & 1) * BH + bh) * T + t) * DH + d;
        const half8 x = *(const half8*)(Obuf + off);
        #pragma unroll
        for (int j = 0; j < 8; ++j) acc[j] += (float)x[j];
        l += (float)lsum[(size_t)(s * BH + bh) * T + t];
    }
    const float inv = 1.0f / l;
    half8 o;
    #pragma unroll
    for (int j = 0; j < 8; ++j) o[j] = (half_t)(acc[j] * inv);
    *(half8*)(AOh + (size_t)r * D + c) = o;
}

// ---------------------------------------------------------------------------
// Output projection: out = AOh(4096x512) @ Wo + bo, fp32 out.
// 32m x 128n, BK=64, dbuf, swizzled.  grid (128, 4).
// ---------------------------------------------------------------------------
__global__ __launch_bounds__(256) void gemm_out(
    const half_t* __restrict__ AOh, const half_t* __restrict__ Wot,
    const float* __restrict__ bo, float* __restrict__ out)
{
    __shared__ half_t As[2][32 * 64];
    __shared__ half_t Bs[2][128 * 64];
    const int tid = threadIdx.x, w = tid >> 6, lane = tid & 63;
    const int l15 = lane & 15, quad = lane >> 4;
    const int m0 = blockIdx.x * 32, n0 = blockIdx.y * 128;

    auto stage = [&](int buf, int k0) {
        {
            const int cid = w * 64 + lane;
            const int r = cid >> 3, c = (cid & 7) ^ (r & 7);
            gl_lds16(AOh + (size_t)(m0 + r) * D + k0 + c * 8,
                     &As[buf][w * 512]);
        }
        #pragma unroll
        for (int s = 0; s < 4; ++s) {
            const int cid = (w * 4 + s) * 64 + lane;
            const int r = cid >> 3, c = (cid & 7) ^ (r & 7);
            gl_lds16(Wot + (size_t)(n0 + r) * D + k0 + c * 8,
                     &Bs[buf][(w * 4 + s) * 512]);
        }
    };

    f32x4 acc[2][2];
    #pragma unroll
    for (int ms = 0; ms < 2; ++ms) { acc[ms][0] = zero4(); acc[ms][1] = zero4(); }

    stage(0, 0);
    __syncthreads();
    for (int it = 0; it < 8; ++it) {
        const int cur = it & 1;
        if (it < 7) stage(cur ^ 1, (it + 1) * 64);
        const int swiz = l15 & 7;
        #pragma unroll
        for (int ks = 0; ks < 2; ++ks) {
            const int c = (ks * 4 + quad) ^ swiz;
            half8 bf[2];
            #pragma unroll
            for (int nt = 0; nt < 2; ++nt)
                bf[nt] = *(const half8*)&Bs[cur][(w * 32 + nt * 16 + l15) * 64 + c * 8];
            #pragma unroll
            for (int ms = 0; ms < 2; ++ms) {
                const half8 af = *(const half8*)&As[cur][(ms * 16 + l15) * 64 + c * 8];
                acc[ms][0] = __builtin_amdgcn_mfma_f32_16x16x32_f16(af, bf[0], acc[ms][0], 0, 0, 0);
                acc[ms][1] = __builtin_amdgcn_mfma_f32_16x16x32_f16(af, bf[1], acc[ms][1], 0, 0, 0);
            }
        }
        __syncthreads();
    }

    float bvv[2];
    #pragma unroll
    for (int nt = 0; nt < 2; ++nt) bvv[nt] = bo[n0 + w * 32 + nt * 16 + l15];
    #pragma unroll
    for (int ms = 0; ms < 2; ++ms)
        #pragma unroll
        for (int nt = 0; nt < 2; ++nt)
            #pragma unroll
            for (int r = 0; r < 4; ++r) {
                const int mrow = m0 + ms * 16 + quad * 4 + r;
                const int n = n0 + w * 32 + nt * 16 + l15;
                out[(size_t)mrow * D + n] = acc[ms][nt][r] + bvv[nt];
            }
}

extern "C" void kernel_launch(void* const* d_in, const int* in_sizes, int n_in,
                              void* d_out, int out_size, void* d_ws, size_t ws_size,
                              hipStream_t stream)
{
    const float* hs   = (const float*)d_in[0];
    const float* Wq   = (const float*)d_in[1];
    const float* bq   = (const float*)d_in[2];
    const float* Wk   = (const float*)d_in[3];
    const float* bk   = (const float*)d_in[4];
    const float* Wv   = (const float*)d_in[5];
    const float* bv   = (const float*)d_in[6];
    const float* Wo   = (const float*)d_in[7];
    const float* bo   = (const float*)d_in[8];
    const float* relb = (const float*)d_in[9];

    // workspace (fp16 elements).  On splits 0,1 live in d_out (8 MB scratch,
    // validated only after the call; gemm_out overwrites it last).
    const size_t NX = (size_t)B * T * D;          // 2,097,152
    half_t* wsh = (half_t*)d_ws;
    half_t* Xh  = wsh;                 // aliased as AOh after gemm_qkv
    half_t* Wts = Xh + NX;             // Wq^T,Wk^T,Wv^T,Wo^T (4*NW)
    half_t* Qh  = Wts + 4 * (size_t)NW;
    half_t* Kh  = Qh + NX;
    half_t* Vth = Kh + NX;
    half_t* On23 = Vth + NX;           // splits 2,3
    half_t* Ls  = On23 + 2 * NX;       // 4*BH*T
    half_t* On01 = (half_t*)d_out;     // splits 0,1 (scratch in d_out)
    half_t* AOh = Xh;

    prep    <<<dim3(1280), 256, 0, stream>>>(hs, Wq, Wk, Wv, Wo, Xh, Wts);
    gemm_qkv<<<dim3(64, 4, 3), 256, 0, stream>>>(Xh, Wts, bq, bk, bv, Qh, Kh, Vth);
    attn_fwd<<<dim3(16, BH, NSPLIT), 256, 0, stream>>>(Qh, Kh, Vth, relb, On01, On23, Ls);
    combine <<<dim3(1024), 256, 0, stream>>>(On01, On23, Ls, AOh);
    gemm_out<<<dim3(128, 4), 256, 0, stream>>>(AOh, Wts + 3 * (size_t)NW, bo, (float*)d_out);
}

// Round 8
// 153.815 us; speedup vs baseline: 1.3019x; 1.3019x over previous
//
#include <hip/hip_runtime.h>
#include <stdint.h>
#include <math.h>

#define H 8
#define DH 64
#define T 2048
#define D 512
#define B 2
#define BH 16
#define MAXREL 32
#define NREL (2*MAXREL+1)
#define C1 0.18033688f           /* 0.125 * log2(e) */
#define NW (D*D)
#define NSPLIT 4

typedef _Float16 half_t;
typedef half_t half8 __attribute__((ext_vector_type(8)));
typedef half_t half4 __attribute__((ext_vector_type(4)));
typedef float f32x4 __attribute__((ext_vector_type(4)));
typedef int int2v __attribute__((ext_vector_type(2)));

typedef __attribute__((address_space(3))) unsigned int lds_uint;
typedef const __attribute__((address_space(1))) unsigned int glb_uint;

__device__ __forceinline__ void gl_lds16(const void* g, void* l) {
    __builtin_amdgcn_global_load_lds((glb_uint*)g, (lds_uint*)l, 16, 0, 0);
}
__device__ __forceinline__ f32x4 zero4() { f32x4 z = {0.f,0.f,0.f,0.f}; return z; }
__device__ __forceinline__ int pkrtz(float a, float b) {
    return __builtin_bit_cast(int, __builtin_amdgcn_cvt_pkrtz(a, b));
}

// ---------------------------------------------------------------------------
// prep: blocks [0,1024): X fp32 -> fp16.  blocks [1024,1280): W^T fp16.
// ---------------------------------------------------------------------------
__global__ __launch_bounds__(256) void prep(
    const float* __restrict__ X,
    const float* __restrict__ Wq, const float* __restrict__ Wk,
    const float* __restrict__ Wv, const float* __restrict__ Wo,
    half_t* __restrict__ Xh, half_t* __restrict__ Wts)
{
    __shared__ half_t Ld[64 * 72];
    const int bid = blockIdx.x;
    const int tid = threadIdx.x;
    if (bid < 1024) {
        const int i = (bid * 256 + tid) * 8;
        const float4 a = *(const float4*)(X + i);
        const float4 b = *(const float4*)(X + i + 4);
        half8 o;
        o[0]=(half_t)a.x; o[1]=(half_t)a.y; o[2]=(half_t)a.z; o[3]=(half_t)a.w;
        o[4]=(half_t)b.x; o[5]=(half_t)b.y; o[6]=(half_t)b.z; o[7]=(half_t)b.w;
        *(half8*)(Xh + i) = o;
    } else {
        const int id = bid - 1024;
        const int z = id >> 6;
        const int tile = id & 63;
        const float* __restrict__ W = (z==0)?Wq:(z==1)?Wk:(z==2)?Wv:Wo;
        half_t* __restrict__ out = Wts + (size_t)z * NW;
        const int k0 = (tile >> 3) * 64;
        const int n0 = (tile & 7) * 64;
        const int r = tid >> 2, c16 = (tid & 3) * 16;
        const float* src = W + (size_t)(k0 + r) * D + n0 + c16;
        #pragma unroll
        for (int j = 0; j < 16; ++j) Ld[r * 72 + c16 + j] = (half_t)src[j];
        __syncthreads();
        half_t tmp[16];
        #pragma unroll
        for (int j = 0; j < 16; ++j) tmp[j] = Ld[(c16 + j) * 72 + r];
        half8* dst = (half8*)(out + (size_t)(n0 + r) * D + k0 + c16);
        dst[0] = *(half8*)&tmp[0];
        dst[1] = *(half8*)&tmp[8];
    }
}

// ---------------------------------------------------------------------------
// QKV GEMM: C = Xh(4096x512) @ W + b.  64m x 128n, BK=64, dbuf staging,
// XOR(r&7)-swizzled 128B LDS rows.  z=0 Q; z=1 K; z=2 V transposed.
// ---------------------------------------------------------------------------
__global__ __launch_bounds__(256) void gemm_qkv(
    const half_t* __restrict__ Xh, const half_t* __restrict__ Wts,
    const float* __restrict__ bq, const float* __restrict__ bk,
    const float* __restrict__ bv,
    half_t* __restrict__ Qh, half_t* __restrict__ Kh, half_t* __restrict__ Vth)
{
    __shared__ half_t As[2][64 * 64];
    __shared__ half_t Bs[2][128 * 64];
    const int tid = threadIdx.x, w = tid >> 6, lane = tid & 63;
    const int l15 = lane & 15, quad = lane >> 4;
    const int m0 = blockIdx.x * 64, n0 = blockIdx.y * 128, z = blockIdx.z;
    const half_t* __restrict__ Wt = Wts + (size_t)z * NW;
    const float* __restrict__ bias = (z==0)?bq:(z==1)?bk:bv;

    auto stage = [&](int buf, int k0) {
        #pragma unroll
        for (int s = 0; s < 2; ++s) {
            const int cid = (w * 2 + s) * 64 + lane;
            const int r = cid >> 3, c = (cid & 7) ^ (r & 7);
            gl_lds16(Xh + (size_t)(m0 + r) * D + k0 + c * 8,
                     &As[buf][(w * 2 + s) * 512]);
        }
        #pragma unroll
        for (int s = 0; s < 4; ++s) {
            const int cid = (w * 4 + s) * 64 + lane;
            const int r = cid >> 3, c = (cid & 7) ^ (r & 7);
            gl_lds16(Wt + (size_t)(n0 + r) * D + k0 + c * 8,
                     &Bs[buf][(w * 4 + s) * 512]);
        }
    };

    f32x4 acc[4][2];
    #pragma unroll
    for (int ms = 0; ms < 4; ++ms) { acc[ms][0] = zero4(); acc[ms][1] = zero4(); }

    stage(0, 0);
    __syncthreads();
    for (int it = 0; it < 8; ++it) {
        const int cur = it & 1;
        if (it < 7) stage(cur ^ 1, (it + 1) * 64);
        const int swiz = l15 & 7;
        #pragma unroll
        for (int ks = 0; ks < 2; ++ks) {
            const int c = (ks * 4 + quad) ^ swiz;
            half8 bf[2];
            #pragma unroll
            for (int nt = 0; nt < 2; ++nt)
                bf[nt] = *(const half8*)&Bs[cur][(w * 32 + nt * 16 + l15) * 64 + c * 8];
            #pragma unroll
            for (int ms = 0; ms < 4; ++ms) {
                const half8 af = *(const half8*)&As[cur][(ms * 16 + l15) * 64 + c * 8];
                acc[ms][0] = __builtin_amdgcn_mfma_f32_16x16x32_f16(af, bf[0], acc[ms][0], 0, 0, 0);
                acc[ms][1] = __builtin_amdgcn_mfma_f32_16x16x32_f16(af, bf[1], acc[ms][1], 0, 0, 0);
            }
        }
        __syncthreads();
    }

    float bvv[2];
    #pragma unroll
    for (int nt = 0; nt < 2; ++nt) bvv[nt] = bias[n0 + w * 32 + nt * 16 + l15];

    if (z == 2) {
        #pragma unroll
        for (int ms = 0; ms < 4; ++ms) {
            const int mbase = m0 + ms * 16 + quad * 4;
            const int bb = mbase >> 11, t0 = mbase & 2047;
            #pragma unroll
            for (int nt = 0; nt < 2; ++nt) {
                const int n = n0 + w * 32 + nt * 16 + l15;
                const int hh = n >> 6, d = n & 63;
                half4 pk;
                #pragma unroll
                for (int r = 0; r < 4; ++r) pk[r] = (half_t)(acc[ms][nt][r] + bvv[nt]);
                *(half4*)(Vth + (((size_t)bb * H + hh) * DH + d) * T + t0) = pk;
            }
        }
    } else {
        half_t* __restrict__ dst = (z == 0) ? Qh : Kh;
        #pragma unroll
        for (int ms = 0; ms < 4; ++ms)
            #pragma unroll
            for (int nt = 0; nt < 2; ++nt)
                #pragma unroll
                for (int r = 0; r < 4; ++r) {
                    const int mrow = m0 + ms * 16 + quad * 4 + r;
                    const int n = n0 + w * 32 + nt * 16 + l15;
                    const int bb = mrow >> 11, t = mrow & 2047, hh = n >> 6, d = n & 63;
                    dst[(((size_t)bb * H + hh) * T + t) * DH + d] = (half_t)(acc[ms][nt][r] + bvv[nt]);
                }
    }
}

// ---------------------------------------------------------------------------
// Flash attention, stage-once / compute-long.  1024-thread block (16 waves x
// 32 q = 512 q), grid (4, 16, 4 splits) = 256 blocks = 1/CU.
// Split = 512 keys, staged in 2 phases of 256 keys (Kt 32KB [key][d] +
// Vt 32KB [d][key], XOR(r&7) 16B-chunk swizzle).  3 barriers total.
// Per 64-key tile: QK^T 16x16x32 (kf b128), exp2 softmax (no max),
// P packs directly into 16x16x16 B-frag (no shuffle), PV 16x16x16
// (vf b64, XOR-spread).  Writes unnormalized O/64 + l/64 fp16.
// ---------------------------------------------------------------------------
__global__ __launch_bounds__(1024, 4) void attn_fwd(
    const half_t* __restrict__ Qh, const half_t* __restrict__ Kh,
    const half_t* __restrict__ Vth, const float* __restrict__ relb,
    half_t* __restrict__ On01, half_t* __restrict__ On23,
    half_t* __restrict__ lsum)
{
    __shared__ half_t Kt[256 * 64];   // [key][d] rows 128B, swizzled chunks
    __shared__ half_t Vt[64 * 256];   // [d][key] rows 512B, swizzled chunks
    __shared__ float rb2[NREL];

    const int tid = threadIdx.x, w = tid >> 6, lane = tid & 63;
    const int l15 = lane & 15, quad = lane >> 4;
    const int qw = blockIdx.x * 512 + w * 32;   // this wave's 32 q-rows
    const int bh = blockIdx.y;
    const int split = blockIdx.z;
    const int kb0 = split * (T / NSPLIT);
    const int h = bh & 7;

    if (tid < NREL) rb2[tid] = relb[h * NREL + tid] * 1.44269504f;

    // Q as B-operand (16x16x32): n=l15, k=ks*32+quad*8
    half8 qf[2][2];
    const half_t* Qbase = Qh + ((size_t)bh * T + qw) * DH;
    #pragma unroll
    for (int g = 0; g < 2; ++g)
        #pragma unroll
        for (int ks = 0; ks < 2; ++ks)
            qf[g][ks] = *(const half8*)(Qbase + (g * 16 + l15) * DH + ks * 32 + quad * 8);

    f32x4 of[2][4];   // [g][d-mtile]; C: col=l15=q, row=quad*4+r=d
    #pragma unroll
    for (int g = 0; g < 2; ++g)
        #pragma unroll
        for (int mt = 0; mt < 4; ++mt) of[g][mt] = zero4();
    float lp[2] = {0.f, 0.f};

    // stage 256 keys (K 32KB + V 32KB) starting at global key pb.
    // 2048 chunks each; wave handles 2 blocks of 64 chunks for K and V.
    auto stage = [&](int pb) {
        #pragma unroll
        for (int s = 0; s < 2; ++s) {
            const int cid = (w * 2 + s) * 64 + lane;        // 0..2047
            const int rk = cid >> 3, ck = (cid & 7) ^ (rk & 7);
            gl_lds16(Kh + ((size_t)bh * T + pb + rk) * DH + ck * 8,
                     &Kt[(w * 2 + s) * 512]);
            const int rv = cid >> 5;
            const int cv = (cid & 24) | ((cid & 7) ^ (rv & 7));
            gl_lds16(Vth + ((size_t)bh * DH + rv) * T + pb + cv * 8,
                     &Vt[(w * 2 + s) * 512]);
        }
    };

    const int swiz = l15 & 7;

    for (int ph = 0; ph < 2; ++ph) {
        const int pb = kb0 + ph * 256;
        if (ph) __syncthreads();        // all waves done with phase 0 data
        stage(pb);
        __syncthreads();                // fill visible

        #pragma unroll
        for (int ktl = 0; ktl < 4; ++ktl) {
            const int kb = pb + ktl * 64;

            // S^T = K . Q^T : A = K-frag (m=key) from LDS
            f32x4 st[2][4];
            #pragma unroll
            for (int g = 0; g < 2; ++g)
                #pragma unroll
                for (int nt = 0; nt < 4; ++nt) st[g][nt] = zero4();
            #pragma unroll
            for (int ks = 0; ks < 2; ++ks) {
                const int c = (ks * 4 + quad) ^ swiz;
                #pragma unroll
                for (int nt = 0; nt < 4; ++nt) {
                    const half8 kf = *(const half8*)&Kt[(ktl * 64 + nt * 16 + l15) * 64 + c * 8];
                    st[0][nt] = __builtin_amdgcn_mfma_f32_16x16x32_f16(kf, qf[0][ks], st[0][nt], 0, 0, 0);
                    st[1][nt] = __builtin_amdgcn_mfma_f32_16x16x32_f16(kf, qf[1][ks], st[1][nt], 0, 0, 0);
                }
            }

            // softmax; pack P directly into 16x16x16 B-frag layout
            half4 pf[2][4];
            const bool uni_hi = (qw - (kb + 63)) >= MAXREL;
            const bool uni_lo = ((qw + 31) - kb) <= -MAXREL;
            if (uni_hi || uni_lo) {
                const float bu = uni_hi ? rb2[NREL - 1] : rb2[0];
                #pragma unroll
                for (int g = 0; g < 2; ++g)
                    #pragma unroll
                    for (int nt = 0; nt < 4; ++nt) {
                        float p[4];
                        #pragma unroll
                        for (int r = 0; r < 4; ++r) p[r] = exp2f(fmaf(st[g][nt][r], C1, bu));
                        lp[g] += (p[0] + p[1]) + (p[2] + p[3]);
                        int2v pk; pk[0] = pkrtz(p[0], p[1]); pk[1] = pkrtz(p[2], p[3]);
                        pf[g][nt] = __builtin_bit_cast(half4, pk);
                    }
            } else {
                #pragma unroll
                for (int g = 0; g < 2; ++g) {
                    const int qg = qw + g * 16 + l15;
                    #pragma unroll
                    for (int nt = 0; nt < 4; ++nt) {
                        float p[4];
                        #pragma unroll
                        for (int r = 0; r < 4; ++r) {
                            const int key = kb + nt * 16 + quad * 4 + r;
                            int rel = qg - key;
                            rel = rel < -MAXREL ? -MAXREL : (rel > MAXREL ? MAXREL : rel);
                            p[r] = exp2f(fmaf(st[g][nt][r], C1, rb2[rel + MAXREL]));
                        }
                        lp[g] += (p[0] + p[1]) + (p[2] + p[3]);
                        int2v pk; pk[0] = pkrtz(p[0], p[1]); pk[1] = pkrtz(p[2], p[3]);
                        pf[g][nt] = __builtin_bit_cast(half4, pk);
                    }
                }
            }

            // O^T += V^T . P^T : A = V^T-frag from LDS (m=d, k=quad*4+j)
            #pragma unroll
            for (int nt = 0; nt < 4; ++nt) {      // key segment (k of PV)
                // 16B-chunk: ktl*8 | ((nt*2 + (quad>>1)) ^ swiz3(row))
                const int cbase = nt * 2 + (quad >> 1);
                const int hoff = (quad & 1) * 4;
                #pragma unroll
                for (int mt = 0; mt < 4; ++mt) {  // d tile
                    const int row = mt * 16 + l15;
                    const int pos = (ktl * 8) | (cbase ^ (row & 7));
                    const half4 vf = *(const half4*)&Vt[row * 256 + pos * 8 + hoff];
                    of[0][mt] = __builtin_amdgcn_mfma_f32_16x16x16f16(vf, pf[0][nt], of[0][mt], 0, 0, 0);
                    of[1][mt] = __builtin_amdgcn_mfma_f32_16x16x16f16(vf, pf[1][nt], of[1][mt], 0, 0, 0);
                }
            }
        }
    }

    // epilogue: lane holds O^T for q = qw + g*16 + l15, d = mt*16 + quad*4 + r
    half_t* Obuf = (split < 2) ? On01 : On23;
    const int sl = split & 1;
    #pragma unroll
    for (int g = 0; g < 2; ++g) {
        const size_t qrow = ((size_t)(sl * BH + bh)) * T + qw + g * 16 + l15;
        half_t* obase = Obuf + qrow * DH;
        #pragma unroll
        for (int mt = 0; mt < 4; ++mt) {
            half4 pk;
            #pragma unroll
            for (int r = 0; r < 4; ++r) pk[r] = (half_t)(of[g][mt][r] * 0.015625f);
            *(half4*)(obase + mt * 16 + quad * 4) = pk;
        }
        float v = lp[g];
        v += __shfl_xor(v, 16);
        v += __shfl_xor(v, 32);
        if (quad == 0)
            lsum[((size_t)(split * BH + bh)) * T + qw + g * 16 + l15] = (half_t)(v * 0.015625f);
    }
}

// ---------------------------------------------------------------------------
// Combine 4 splits: AOh[t][h*64+d] = sum(O_s)/sum(l_s), fp16.  grid 1024x256.
// ---------------------------------------------------------------------------
__global__ __launch_bounds__(256) void combine(
    const half_t* __restrict__ On01, const half_t* __restrict__ On23,
    const half_t* __restrict__ lsum, half_t* __restrict__ AOh)
{
    const int i = blockIdx.x * 256 + threadIdx.x;
    const int r = i >> 6;
    const int c = (i & 63) * 8;
    const int b = r >> 11, t = r & 2047, hh = c >> 6, d = c & 63;
    const int bh = b * H + hh;
    float acc[8] = {};
    float l = 0.f;
    #pragma unroll
    for (int s = 0; s < NSPLIT; ++s) {
        const half_t* Obuf = (s < 2) ? On01 : On23;
        const size_t off = ((size_t)((s & 1) * BH + bh) * T + t) * DH + d;
        const half8 x = *(const half8*)(Obuf + off);
        #pragma unroll
        for (int j = 0; j < 8; ++j) acc[j] += (float)x[j];
        l += (float)lsum[(size_t)(s * BH + bh) * T + t];
    }
    const float inv = 1.0f / l;
    half8 o;
    #pragma unroll
    for (int j = 0; j < 8; ++j) o[j] = (half_t)(acc[j] * inv);
    *(half8*)(AOh + (size_t)r * D + c) = o;
}

// ---------------------------------------------------------------------------
// Output projection: out = AOh(4096x512) @ Wo + bo, fp32 out.
// 32m x 128n, BK=64, dbuf, swizzled.  grid (128, 4).
// ---------------------------------------------------------------------------
__global__ __launch_bounds__(256) void gemm_out(
    const half_t* __restrict__ AOh, const half_t* __restrict__ Wot,
    const float* __restrict__ bo, float* __restrict__ out)
{
    __shared__ half_t As[2][32 * 64];
    __shared__ half_t Bs[2][128 * 64];
    const int tid = threadIdx.x, w = tid >> 6, lane = tid & 63;
    const int l15 = lane & 15, quad = lane >> 4;
    const int m0 = blockIdx.x * 32, n0 = blockIdx.y * 128;

    auto stage = [&](int buf, int k0) {
        {
            const int cid = w * 64 + lane;
            const int r = cid >> 3, c = (cid & 7) ^ (r & 7);
            gl_lds16(AOh + (size_t)(m0 + r) * D + k0 + c * 8,
                     &As[buf][w * 512]);
        }
        #pragma unroll
        for (int s = 0; s < 4; ++s) {
            const int cid = (w * 4 + s) * 64 + lane;
            const int r = cid >> 3, c = (cid & 7) ^ (r & 7);
            gl_lds16(Wot + (size_t)(n0 + r) * D + k0 + c * 8,
                     &Bs[buf][(w * 4 + s) * 512]);
        }
    };

    f32x4 acc[2][2];
    #pragma unroll
    for (int ms = 0; ms < 2; ++ms) { acc[ms][0] = zero4(); acc[ms][1] = zero4(); }

    stage(0, 0);
    __syncthreads();
    for (int it = 0; it < 8; ++it) {
        const int cur = it & 1;
        if (it < 7) stage(cur ^ 1, (it + 1) * 64);
        const int swiz = l15 & 7;
        #pragma unroll
        for (int ks = 0; ks < 2; ++ks) {
            const int c = (ks * 4 + quad) ^ swiz;
            half8 bf[2];
            #pragma unroll
            for (int nt = 0; nt < 2; ++nt)
                bf[nt] = *(const half8*)&Bs[cur][(w * 32 + nt * 16 + l15) * 64 + c * 8];
            #pragma unroll
            for (int ms = 0; ms < 2; ++ms) {
                const half8 af = *(const half8*)&As[cur][(ms * 16 + l15) * 64 + c * 8];
                acc[ms][0] = __builtin_amdgcn_mfma_f32_16x16x32_f16(af, bf[0], acc[ms][0], 0, 0, 0);
                acc[ms][1] = __builtin_amdgcn_mfma_f32_16x16x32_f16(af, bf[1], acc[ms][1], 0, 0, 0);
            }
        }
        __syncthreads();
    }

    float bvv[2];
    #pragma unroll
    for (int nt = 0; nt < 2; ++nt) bvv[nt] = bo[n0 + w * 32 + nt * 16 + l15];
    #pragma unroll
    for (int ms = 0; ms < 2; ++ms)
        #pragma unroll
        for (int nt = 0; nt < 2; ++nt)
            #pragma unroll
            for (int r = 0; r < 4; ++r) {
                const int mrow = m0 + ms * 16 + quad * 4 + r;
                const int n = n0 + w * 32 + nt * 16 + l15;
                out[(size_t)mrow * D + n] = acc[ms][nt][r] + bvv[nt];
            }
}

extern "C" void kernel_launch(void* const* d_in, const int* in_sizes, int n_in,
                              void* d_out, int out_size, void* d_ws, size_t ws_size,
                              hipStream_t stream)
{
    const float* hs   = (const float*)d_in[0];
    const float* Wq   = (const float*)d_in[1];
    const float* bq   = (const float*)d_in[2];
    const float* Wk   = (const float*)d_in[3];
    const float* bk   = (const float*)d_in[4];
    const float* Wv   = (const float*)d_in[5];
    const float* bv   = (const float*)d_in[6];
    const float* Wo   = (const float*)d_in[7];
    const float* bo   = (const float*)d_in[8];
    const float* relb = (const float*)d_in[9];

    // workspace (fp16 elements).  On splits 0,1 live in d_out (8 MB scratch,
    // validated only after the call; gemm_out overwrites it last).
    const size_t NX = (size_t)B * T * D;          // 2,097,152
    half_t* wsh = (half_t*)d_ws;
    half_t* Xh  = wsh;                 // aliased as AOh after gemm_qkv
    half_t* Wts = Xh + NX;             // Wq^T,Wk^T,Wv^T,Wo^T (4*NW)
    half_t* Qh  = Wts + 4 * (size_t)NW;
    half_t* Kh  = Qh + NX;
    half_t* Vth = Kh + NX;
    half_t* On23 = Vth + NX;           // splits 2,3
    half_t* Ls  = On23 + 2 * NX;       // 4*BH*T
    half_t* On01 = (half_t*)d_out;     // splits 0,1 (scratch in d_out)
    half_t* AOh = Xh;

    prep    <<<dim3(1280), 256, 0, stream>>>(hs, Wq, Wk, Wv, Wo, Xh, Wts);
    gemm_qkv<<<dim3(64, 4, 3), 256, 0, stream>>>(Xh, Wts, bq, bk, bv, Qh, Kh, Vth);
    attn_fwd<<<dim3(4, BH, NSPLIT), 1024, 0, stream>>>(Qh, Kh, Vth, relb, On01, On23, Ls);
    combine <<<dim3(1024), 256, 0, stream>>>(On01, On23, Ls, AOh);
    gemm_out<<<dim3(128, 4), 256, 0, stream>>>(AOh, Wts + 3 * (size_t)NW, bo, (float*)d_out);
}

// Round 9
// 147.571 us; speedup vs baseline: 1.3570x; 1.0423x over previous
//
#include <hip/hip_runtime.h>
#include <stdint.h>
#include <math.h>

#define H 8
#define DH 64
#define T 2048
#define D 512
#define B 2
#define BH 16
#define MAXREL 32
#define NREL (2*MAXREL+1)
#define C1 0.18033688f           /* 0.125 * log2(e) */
#define NW (D*D)
#define NSPLIT 4

typedef _Float16 half_t;
typedef half_t half8 __attribute__((ext_vector_type(8)));
typedef half_t half4 __attribute__((ext_vector_type(4)));
typedef float f32x4 __attribute__((ext_vector_type(4)));
typedef int int2v __attribute__((ext_vector_type(2)));

typedef __attribute__((address_space(3))) unsigned int lds_uint;
typedef const __attribute__((address_space(1))) unsigned int glb_uint;

__device__ __forceinline__ void gl_lds16(const void* g, void* l) {
    __builtin_amdgcn_global_load_lds((glb_uint*)g, (lds_uint*)l, 16, 0, 0);
}
__device__ __forceinline__ f32x4 zero4() { f32x4 z = {0.f,0.f,0.f,0.f}; return z; }
__device__ __forceinline__ int pkrtz(float a, float b) {
    return __builtin_bit_cast(int, __builtin_amdgcn_cvt_pkrtz(a, b));
}
__device__ __forceinline__ float fexp2(float x) {
#if defined(__HIP_DEVICE_COMPILE__) && __has_builtin(__builtin_amdgcn_exp2f)
    return __builtin_amdgcn_exp2f(x);   // raw v_exp_f32, skips OCML guards
#else
    return exp2f(x);
#endif
}

// ---------------------------------------------------------------------------
// prep: blocks [0,1024): X fp32 -> fp16.  blocks [1024,1280): W^T fp16.
// ---------------------------------------------------------------------------
__global__ __launch_bounds__(256) void prep(
    const float* __restrict__ X,
    const float* __restrict__ Wq, const float* __restrict__ Wk,
    const float* __restrict__ Wv, const float* __restrict__ Wo,
    half_t* __restrict__ Xh, half_t* __restrict__ Wts)
{
    __shared__ half_t Ld[64 * 72];
    const int bid = blockIdx.x;
    const int tid = threadIdx.x;
    if (bid < 1024) {
        const int i = (bid * 256 + tid) * 8;
        const float4 a = *(const float4*)(X + i);
        const float4 b = *(const float4*)(X + i + 4);
        half8 o;
        o[0]=(half_t)a.x; o[1]=(half_t)a.y; o[2]=(half_t)a.z; o[3]=(half_t)a.w;
        o[4]=(half_t)b.x; o[5]=(half_t)b.y; o[6]=(half_t)b.z; o[7]=(half_t)b.w;
        *(half8*)(Xh + i) = o;
    } else {
        const int id = bid - 1024;
        const int z = id >> 6;
        const int tile = id & 63;
        const float* __restrict__ W = (z==0)?Wq:(z==1)?Wk:(z==2)?Wv:Wo;
        half_t* __restrict__ out = Wts + (size_t)z * NW;
        const int k0 = (tile >> 3) * 64;
        const int n0 = (tile & 7) * 64;
        const int r = tid >> 2, c16 = (tid & 3) * 16;
        const float* src = W + (size_t)(k0 + r) * D + n0 + c16;
        #pragma unroll
        for (int j = 0; j < 16; ++j) Ld[r * 72 + c16 + j] = (half_t)src[j];
        __syncthreads();
        half_t tmp[16];
        #pragma unroll
        for (int j = 0; j < 16; ++j) tmp[j] = Ld[(c16 + j) * 72 + r];
        half8* dst = (half8*)(out + (size_t)(n0 + r) * D + k0 + c16);
        dst[0] = *(half8*)&tmp[0];
        dst[1] = *(half8*)&tmp[8];
    }
}

// ---------------------------------------------------------------------------
// QKV GEMM: C = Xh(4096x512) @ W + b.  128m x 128n tile, BK=64, dbuf,
// XOR(r&7)-swizzled 128B LDS rows, 4 waves in 2x2 (each staged frag read by
// 2 waves -> MFMA:LDS-read 2:1).  z=0 Q; z=1 K; z=2 V transposed.
// grid (32, 4, 3).
// ---------------------------------------------------------------------------
__global__ __launch_bounds__(256) void gemm_qkv(
    const half_t* __restrict__ Xh, const half_t* __restrict__ Wts,
    const float* __restrict__ bq, const float* __restrict__ bk,
    const float* __restrict__ bv,
    half_t* __restrict__ Qh, half_t* __restrict__ Kh, half_t* __restrict__ Vth)
{
    __shared__ half_t As[2][128 * 64];
    __shared__ half_t Bs[2][128 * 64];
    const int tid = threadIdx.x, w = tid >> 6, lane = tid & 63;
    const int l15 = lane & 15, quad = lane >> 4;
    const int m0 = blockIdx.x * 128, n0 = blockIdx.y * 128, z = blockIdx.z;
    const half_t* __restrict__ Wt = Wts + (size_t)z * NW;
    const float* __restrict__ bias = (z==0)?bq:(z==1)?bk:bv;
    const int mw = (w >> 1) * 64, nw = (w & 1) * 64;

    auto stage = [&](int buf, int k0) {
        #pragma unroll
        for (int s = 0; s < 4; ++s) {
            const int cid = (w * 4 + s) * 64 + lane;       // 0..1023 chunks
            const int r = cid >> 3, c = (cid & 7) ^ (r & 7);
            gl_lds16(Xh + (size_t)(m0 + r) * D + k0 + c * 8,
                     &As[buf][(w * 4 + s) * 512]);
            gl_lds16(Wt + (size_t)(n0 + r) * D + k0 + c * 8,
                     &Bs[buf][(w * 4 + s) * 512]);
        }
    };

    f32x4 acc[4][4];
    #pragma unroll
    for (int i = 0; i < 4; ++i)
        #pragma unroll
        for (int j = 0; j < 4; ++j) acc[i][j] = zero4();

    stage(0, 0);
    __syncthreads();
    for (int it = 0; it < 8; ++it) {
        const int cur = it & 1;
        if (it < 7) stage(cur ^ 1, (it + 1) * 64);
        const int swiz = l15 & 7;
        #pragma unroll
        for (int ks = 0; ks < 2; ++ks) {
            const int c = (ks * 4 + quad) ^ swiz;
            half8 af[4], bf[4];
            #pragma unroll
            for (int i = 0; i < 4; ++i)
                af[i] = *(const half8*)&As[cur][(mw + i * 16 + l15) * 64 + c * 8];
            #pragma unroll
            for (int j = 0; j < 4; ++j)
                bf[j] = *(const half8*)&Bs[cur][(nw + j * 16 + l15) * 64 + c * 8];
            #pragma unroll
            for (int i = 0; i < 4; ++i)
                #pragma unroll
                for (int j = 0; j < 4; ++j)
                    acc[i][j] = __builtin_amdgcn_mfma_f32_16x16x32_f16(af[i], bf[j], acc[i][j], 0, 0, 0);
        }
        __syncthreads();
    }

    float bvv[4];
    #pragma unroll
    for (int j = 0; j < 4; ++j) bvv[j] = bias[n0 + nw + j * 16 + l15];

    if (z == 2) {
        #pragma unroll
        for (int i = 0; i < 4; ++i) {
            const int mbase = m0 + mw + i * 16 + quad * 4;
            const int bb = mbase >> 11, t0 = mbase & 2047;
            #pragma unroll
            for (int j = 0; j < 4; ++j) {
                const int n = n0 + nw + j * 16 + l15;
                const int hh = n >> 6, d = n & 63;
                half4 pk;
                #pragma unroll
                for (int r = 0; r < 4; ++r) pk[r] = (half_t)(acc[i][j][r] + bvv[j]);
                *(half4*)(Vth + (((size_t)bb * H + hh) * DH + d) * T + t0) = pk;
            }
        }
    } else {
        half_t* __restrict__ dst = (z == 0) ? Qh : Kh;
        #pragma unroll
        for (int i = 0; i < 4; ++i)
            #pragma unroll
            for (int j = 0; j < 4; ++j)
                #pragma unroll
                for (int r = 0; r < 4; ++r) {
                    const int mrow = m0 + mw + i * 16 + quad * 4 + r;
                    const int n = n0 + nw + j * 16 + l15;
                    const int bb = mrow >> 11, t = mrow & 2047, hh = n >> 6, d = n & 63;
                    dst[(((size_t)bb * H + hh) * T + t) * DH + d] = (half_t)(acc[i][j][r] + bvv[j]);
                }
    }
}

// ---------------------------------------------------------------------------
// Flash attention, stage-once / compute-long (R8 structure, raw v_exp_f32).
// 1024-thread block (16 waves x 32 q), grid (4, 16, 4 splits) = 256 blocks.
// ---------------------------------------------------------------------------
__global__ __launch_bounds__(1024, 4) void attn_fwd(
    const half_t* __restrict__ Qh, const half_t* __restrict__ Kh,
    const half_t* __restrict__ Vth, const float* __restrict__ relb,
    half_t* __restrict__ On01, half_t* __restrict__ On23,
    half_t* __restrict__ lsum)
{
    __shared__ half_t Kt[256 * 64];   // [key][d] rows 128B, swizzled chunks
    __shared__ half_t Vt[64 * 256];   // [d][key] rows 512B, swizzled chunks
    __shared__ float rb2[NREL];

    const int tid = threadIdx.x, w = tid >> 6, lane = tid & 63;
    const int l15 = lane & 15, quad = lane >> 4;
    const int qw = blockIdx.x * 512 + w * 32;   // this wave's 32 q-rows
    const int bh = blockIdx.y;
    const int split = blockIdx.z;
    const int kb0 = split * (T / NSPLIT);
    const int h = bh & 7;

    if (tid < NREL) rb2[tid] = relb[h * NREL + tid] * 1.44269504f;

    // Q as B-operand (16x16x32): n=l15, k=ks*32+quad*8
    half8 qf[2][2];
    const half_t* Qbase = Qh + ((size_t)bh * T + qw) * DH;
    #pragma unroll
    for (int g = 0; g < 2; ++g)
        #pragma unroll
        for (int ks = 0; ks < 2; ++ks)
            qf[g][ks] = *(const half8*)(Qbase + (g * 16 + l15) * DH + ks * 32 + quad * 8);

    f32x4 of[2][4];   // [g][d-mtile]; C: col=l15=q, row=quad*4+r=d
    #pragma unroll
    for (int g = 0; g < 2; ++g)
        #pragma unroll
        for (int mt = 0; mt < 4; ++mt) of[g][mt] = zero4();
    float lp[2] = {0.f, 0.f};

    auto stage = [&](int pb) {
        #pragma unroll
        for (int s = 0; s < 2; ++s) {
            const int cid = (w * 2 + s) * 64 + lane;        // 0..2047
            const int rk = cid >> 3, ck = (cid & 7) ^ (rk & 7);
            gl_lds16(Kh + ((size_t)bh * T + pb + rk) * DH + ck * 8,
                     &Kt[(w * 2 + s) * 512]);
            const int rv = cid >> 5;
            const int cv = (cid & 24) | ((cid & 7) ^ (rv & 7));
            gl_lds16(Vth + ((size_t)bh * DH + rv) * T + pb + cv * 8,
                     &Vt[(w * 2 + s) * 512]);
        }
    };

    const int swiz = l15 & 7;

    for (int ph = 0; ph < 2; ++ph) {
        const int pb = kb0 + ph * 256;
        if (ph) __syncthreads();
        stage(pb);
        __syncthreads();

        #pragma unroll
        for (int ktl = 0; ktl < 4; ++ktl) {
            const int kb = pb + ktl * 64;

            // S^T = K . Q^T
            f32x4 st[2][4];
            #pragma unroll
            for (int g = 0; g < 2; ++g)
                #pragma unroll
                for (int nt = 0; nt < 4; ++nt) st[g][nt] = zero4();
            #pragma unroll
            for (int ks = 0; ks < 2; ++ks) {
                const int c = (ks * 4 + quad) ^ swiz;
                #pragma unroll
                for (int nt = 0; nt < 4; ++nt) {
                    const half8 kf = *(const half8*)&Kt[(ktl * 64 + nt * 16 + l15) * 64 + c * 8];
                    st[0][nt] = __builtin_amdgcn_mfma_f32_16x16x32_f16(kf, qf[0][ks], st[0][nt], 0, 0, 0);
                    st[1][nt] = __builtin_amdgcn_mfma_f32_16x16x32_f16(kf, qf[1][ks], st[1][nt], 0, 0, 0);
                }
            }

            // softmax; pack P directly into 16x16x16 B-frag layout
            half4 pf[2][4];
            const bool uni_hi = (qw - (kb + 63)) >= MAXREL;
            const bool uni_lo = ((qw + 31) - kb) <= -MAXREL;
            if (uni_hi || uni_lo) {
                const float bu = uni_hi ? rb2[NREL - 1] : rb2[0];
                #pragma unroll
                for (int g = 0; g < 2; ++g)
                    #pragma unroll
                    for (int nt = 0; nt < 4; ++nt) {
                        float p[4];
                        #pragma unroll
                        for (int r = 0; r < 4; ++r) p[r] = fexp2(fmaf(st[g][nt][r], C1, bu));
                        lp[g] += (p[0] + p[1]) + (p[2] + p[3]);
                        int2v pk; pk[0] = pkrtz(p[0], p[1]); pk[1] = pkrtz(p[2], p[3]);
                        pf[g][nt] = __builtin_bit_cast(half4, pk);
                    }
            } else {
                #pragma unroll
                for (int g = 0; g < 2; ++g) {
                    const int qg = qw + g * 16 + l15;
                    #pragma unroll
                    for (int nt = 0; nt < 4; ++nt) {
                        float p[4];
                        #pragma unroll
                        for (int r = 0; r < 4; ++r) {
                            const int key = kb + nt * 16 + quad * 4 + r;
                            int rel = qg - key;
                            rel = rel < -MAXREL ? -MAXREL : (rel > MAXREL ? MAXREL : rel);
                            p[r] = fexp2(fmaf(st[g][nt][r], C1, rb2[rel + MAXREL]));
                        }
                        lp[g] += (p[0] + p[1]) + (p[2] + p[3]);
                        int2v pk; pk[0] = pkrtz(p[0], p[1]); pk[1] = pkrtz(p[2], p[3]);
                        pf[g][nt] = __builtin_bit_cast(half4, pk);
                    }
                }
            }

            // O^T += V^T . P^T
            #pragma unroll
            for (int nt = 0; nt < 4; ++nt) {
                const int cbase = nt * 2 + (quad >> 1);
                const int hoff = (quad & 1) * 4;
                #pragma unroll
                for (int mt = 0; mt < 4; ++mt) {
                    const int row = mt * 16 + l15;
                    const int pos = (ktl * 8) | (cbase ^ (row & 7));
                    const half4 vf = *(const half4*)&Vt[row * 256 + pos * 8 + hoff];
                    of[0][mt] = __builtin_amdgcn_mfma_f32_16x16x16f16(vf, pf[0][nt], of[0][mt], 0, 0, 0);
                    of[1][mt] = __builtin_amdgcn_mfma_f32_16x16x16f16(vf, pf[1][nt], of[1][mt], 0, 0, 0);
                }
            }
        }
    }

    // epilogue
    half_t* Obuf = (split < 2) ? On01 : On23;
    const int sl = split & 1;
    #pragma unroll
    for (int g = 0; g < 2; ++g) {
        const size_t qrow = ((size_t)(sl * BH + bh)) * T + qw + g * 16 + l15;
        half_t* obase = Obuf + qrow * DH;
        #pragma unroll
        for (int mt = 0; mt < 4; ++mt) {
            half4 pk;
            #pragma unroll
            for (int r = 0; r < 4; ++r) pk[r] = (half_t)(of[g][mt][r] * 0.015625f);
            *(half4*)(obase + mt * 16 + quad * 4) = pk;
        }
        float v = lp[g];
        v += __shfl_xor(v, 16);
        v += __shfl_xor(v, 32);
        if (quad == 0)
            lsum[((size_t)(split * BH + bh)) * T + qw + g * 16 + l15] = (half_t)(v * 0.015625f);
    }
}

// ---------------------------------------------------------------------------
// Combine 4 splits: AOh[t][h*64+d] = sum(O_s)/sum(l_s), fp16.  grid 1024x256.
// ---------------------------------------------------------------------------
__global__ __launch_bounds__(256) void combine(
    const half_t* __restrict__ On01, const half_t* __restrict__ On23,
    const half_t* __restrict__ lsum, half_t* __restrict__ AOh)
{
    const int i = blockIdx.x * 256 + threadIdx.x;
    const int r = i >> 6;
    const int c = (i & 63) * 8;
    const int b = r >> 11, t = r & 2047, hh = c >> 6, d = c & 63;
    const int bh = b * H + hh;
    float acc[8] = {};
    float l = 0.f;
    #pragma unroll
    for (int s = 0; s < NSPLIT; ++s) {
        const half_t* Obuf = (s < 2) ? On01 : On23;
        const size_t off = ((size_t)((s & 1) * BH + bh) * T + t) * DH + d;
        const half8 x = *(const half8*)(Obuf + off);
        #pragma unroll
        for (int j = 0; j < 8; ++j) acc[j] += (float)x[j];
        l += (float)lsum[(size_t)(s * BH + bh) * T + t];
    }
    const float inv = 1.0f / l;
    half8 o;
    #pragma unroll
    for (int j = 0; j < 8; ++j) o[j] = (half_t)(acc[j] * inv);
    *(half8*)(AOh + (size_t)r * D + c) = o;
}

// ---------------------------------------------------------------------------
// Output projection: out = AOh(4096x512) @ Wo + bo, fp32 out.
// 32m x 128n, BK=64, dbuf, swizzled.  grid (128, 4).
// ---------------------------------------------------------------------------
__global__ __launch_bounds__(256) void gemm_out(
    const half_t* __restrict__ AOh, const half_t* __restrict__ Wot,
    const float* __restrict__ bo, float* __restrict__ out)
{
    __shared__ half_t As[2][32 * 64];
    __shared__ half_t Bs[2][128 * 64];
    const int tid = threadIdx.x, w = tid >> 6, lane = tid & 63;
    const int l15 = lane & 15, quad = lane >> 4;
    const int m0 = blockIdx.x * 32, n0 = blockIdx.y * 128;

    auto stage = [&](int buf, int k0) {
        {
            const int cid = w * 64 + lane;
            const int r = cid >> 3, c = (cid & 7) ^ (r & 7);
            gl_lds16(AOh + (size_t)(m0 + r) * D + k0 + c * 8,
                     &As[buf][w * 512]);
        }
        #pragma unroll
        for (int s = 0; s < 4; ++s) {
            const int cid = (w * 4 + s) * 64 + lane;
            const int r = cid >> 3, c = (cid & 7) ^ (r & 7);
            gl_lds16(Wot + (size_t)(n0 + r) * D + k0 + c * 8,
                     &Bs[buf][(w * 4 + s) * 512]);
        }
    };

    f32x4 acc[2][2];
    #pragma unroll
    for (int ms = 0; ms < 2; ++ms) { acc[ms][0] = zero4(); acc[ms][1] = zero4(); }

    stage(0, 0);
    __syncthreads();
    for (int it = 0; it < 8; ++it) {
        const int cur = it & 1;
        if (it < 7) stage(cur ^ 1, (it + 1) * 64);
        const int swiz = l15 & 7;
        #pragma unroll
        for (int ks = 0; ks < 2; ++ks) {
            const int c = (ks * 4 + quad) ^ swiz;
            half8 bf[2];
            #pragma unroll
            for (int nt = 0; nt < 2; ++nt)
                bf[nt] = *(const half8*)&Bs[cur][(w * 32 + nt * 16 + l15) * 64 + c * 8];
            #pragma unroll
            for (int ms = 0; ms < 2; ++ms) {
                const half8 af = *(const half8*)&As[cur][(ms * 16 + l15) * 64 + c * 8];
                acc[ms][0] = __builtin_amdgcn_mfma_f32_16x16x32_f16(af, bf[0], acc[ms][0], 0, 0, 0);
                acc[ms][1] = __builtin_amdgcn_mfma_f32_16x16x32_f16(af, bf[1], acc[ms][1], 0, 0, 0);
            }
        }
        __syncthreads();
    }

    float bvv[2];
    #pragma unroll
    for (int nt = 0; nt < 2; ++nt) bvv[nt] = bo[n0 + w * 32 + nt * 16 + l15];
    #pragma unroll
    for (int ms = 0; ms < 2; ++ms)
        #pragma unroll
        for (int nt = 0; nt < 2; ++nt)
            #pragma unroll
            for (int r = 0; r < 4; ++r) {
                const int mrow = m0 + ms * 16 + quad * 4 + r;
                const int n = n0 + w * 32 + nt * 16 + l15;
                out[(size_t)mrow * D + n] = acc[ms][nt][r] + bvv[nt];
            }
}

extern "C" void kernel_launch(void* const* d_in, const int* in_sizes, int n_in,
                              void* d_out, int out_size, void* d_ws, size_t ws_size,
                              hipStream_t stream)
{
    const float* hs   = (const float*)d_in[0];
    const float* Wq   = (const float*)d_in[1];
    const float* bq   = (const float*)d_in[2];
    const float* Wk   = (const float*)d_in[3];
    const float* bk   = (const float*)d_in[4];
    const float* Wv   = (const float*)d_in[5];
    const float* bv   = (const float*)d_in[6];
    const float* Wo   = (const float*)d_in[7];
    const float* bo   = (const float*)d_in[8];
    const float* relb = (const float*)d_in[9];

    // workspace (fp16 elements).  On splits 0,1 live in d_out (8 MB scratch,
    // validated only after the call; gemm_out overwrites it last).
    const size_t NX = (size_t)B * T * D;          // 2,097,152
    half_t* wsh = (half_t*)d_ws;
    half_t* Xh  = wsh;                 // aliased as AOh after gemm_qkv
    half_t* Wts = Xh + NX;             // Wq^T,Wk^T,Wv^T,Wo^T (4*NW)
    half_t* Qh  = Wts + 4 * (size_t)NW;
    half_t* Kh  = Qh + NX;
    half_t* Vth = Kh + NX;
    half_t* On23 = Vth + NX;           // splits 2,3
    half_t* Ls  = On23 + 2 * NX;       // 4*BH*T
    half_t* On01 = (half_t*)d_out;     // splits 0,1 (scratch in d_out)
    half_t* AOh = Xh;

    prep    <<<dim3(1280), 256, 0, stream>>>(hs, Wq, Wk, Wv, Wo, Xh, Wts);
    gemm_qkv<<<dim3(32, 4, 3), 256, 0, stream>>>(Xh, Wts, bq, bk, bv, Qh, Kh, Vth);
    attn_fwd<<<dim3(4, BH, NSPLIT), 1024, 0, stream>>>(Qh, Kh, Vth, relb, On01, On23, Ls);
    combine <<<dim3(1024), 256, 0, stream>>>(On01, On23, Ls, AOh);
    gemm_out<<<dim3(128, 4), 256, 0, stream>>>(AOh, Wts + 3 * (size_t)NW, bo, (float*)d_out);
}